// Round 15
// baseline (282.490 us; speedup 1.0000x reference)
//
#include <hip/hip_runtime.h>
#include <hip/hip_bf16.h>
#include <cstdint>
#include <cstddef>

#define S_LEN 2048
#define NEGV -1e9f
#define QKV_STRIDE 5120

using bf16x8   = __attribute__((ext_vector_type(8))) __bf16;
using bf16x4   = __attribute__((ext_vector_type(4))) __bf16;
using ushort8  = __attribute__((ext_vector_type(8))) unsigned short;
using ushort4v = __attribute__((ext_vector_type(4))) unsigned short;
using f32x4    = __attribute__((ext_vector_type(4))) float;
using uint2v   = __attribute__((ext_vector_type(2))) unsigned int;

template<bool V> struct BoolC { static constexpr bool value = V; };
template<int V>  struct IntC  { static constexpr int  value = V; };

__device__ __forceinline__ unsigned short f2bf(float f) {
    union { float f; unsigned u; } v; v.f = f;
    unsigned u = v.u;
    return (unsigned short)((u + 0x7fffu + ((u >> 16) & 1u)) >> 16);
}

__device__ __forceinline__ float bf2f(unsigned short u) {
    union { unsigned u; float f; } cv; cv.u = (unsigned)u << 16;
    return cv.f;
}

// pack two positive floats -> {bf16(b),bf16(a)} with round-half-up via v_perm
__device__ __forceinline__ unsigned pk2bf(float a, float b) {
    unsigned ua = __builtin_bit_cast(unsigned, a) + 0x8000u;
    unsigned ub = __builtin_bit_cast(unsigned, b) + 0x8000u;
    return __builtin_amdgcn_perm(ub, ua, 0x07060302u);
}

__device__ __forceinline__ void gld_lds16(const unsigned short* g, unsigned short* l) {
    __builtin_amdgcn_global_load_lds(
        (const __attribute__((address_space(1))) void*)(g),
        (__attribute__((address_space(3))) void*)(l), 16, 0, 0);
}

__device__ __forceinline__ f32x4 mfma32(bf16x8 a, bf16x8 b, f32x4 c) {
    return __builtin_amdgcn_mfma_f32_16x16x32_bf16(a, b, c, 0, 0, 0);
}

__device__ __forceinline__ f32x4 mfma16(ushort4v a, ushort4v b, f32x4 c) {
#if __has_builtin(__builtin_amdgcn_mfma_f32_16x16x16_bf16)
    return __builtin_amdgcn_mfma_f32_16x16x16_bf16(
        __builtin_bit_cast(bf16x4, a), __builtin_bit_cast(bf16x4, b), c, 0, 0, 0);
#else
    return __builtin_amdgcn_mfma_f32_16x16x16bf16_1k(
        __builtin_bit_cast(bf16x4, a), __builtin_bit_cast(bf16x4, b), c, 0, 0, 0);
#endif
}

// ------------- fused fp32->bf16 convert (blocks 0..10239) + lamcolt (blocks 10240+) -
__global__ __launch_bounds__(256) void cvt5lam_kernel(
    const float* __restrict__ X,  const float* __restrict__ Wq,
    const float* __restrict__ Wk, const float* __restrict__ Wv,
    const float* __restrict__ Wo,
    unsigned short* __restrict__ Xb, unsigned short* __restrict__ Wqkvb,
    unsigned short* __restrict__ Wob,
    const float* __restrict__ lq1, const float* __restrict__ lk1,
    const float* __restrict__ lq2, const float* __restrict__ lk2,
    const int* __restrict__ tok, const float* __restrict__ amask,
    float* __restrict__ lam_ws, float* __restrict__ sum_ws,
    float* __restrict__ sumsq_ws, float* __restrict__ colt_g) {
    if (blockIdx.x < 10240) {
        int i = blockIdx.x * 256 + threadIdx.x;   // float4 index, total 2621440
        const float* src; unsigned short* dst; int off;
        if      (i < 1048576) { src = X;  dst = Xb;              off = 0;       }
        else if (i < 1572864) { src = Wq; dst = Wqkvb;           off = 1048576; }
        else if (i < 2097152) { src = Wk; dst = Wqkvb + 2097152; off = 1572864; }
        else if (i < 2359296) { src = Wv; dst = Wqkvb + 4194304; off = 2097152; }
        else                  { src = Wo; dst = Wob;             off = 2359296; }
        int j = i - off;
        float4 v = ((const float4*)src)[j];
        ushort4v t;
        t.x = f2bf(v.x); t.y = f2bf(v.y); t.z = f2bf(v.z); t.w = f2bf(v.w);
        ((ushort4v*)dst)[j] = t;
        return;
    }
    const int bid2 = blockIdx.x - 10240;          // 0..63: lamcolt part
    const int gid = bid2 * 256 + threadIdx.x;
    if (bid2 == 0) {
        int t = threadIdx.x;
        if (t >= 64 && t < 96)  sum_ws[t - 64] = 0.f;
        if (t >= 96 && t < 128) sumsq_ws[t - 96] = 0.f;
        if (t < 64) {
            float a = lq1[t] * lk1[t];
            float b = lq2[t] * lk2[t];
            for (int off = 32; off > 0; off >>= 1) {
                a += __shfl_xor(a, off);
                b += __shfl_xor(b, off);
            }
            if (t == 0) lam_ws[0] = __expf(a) - __expf(b) + 0.8f;
        }
    }
    const int b = gid >> 13, h = (gid >> 9) & 15, k = (gid & 511) * 4;
    const float slope2 = exp2f(-0.5f * (float)(h + 1)) * 1.44269504f;
    int4   t4 = *(const int4*)(tok + b * S_LEN + k);
    float4 a4 = *(const float4*)(amask + b * S_LEN + k);
    float4 o;
    o.x = slope2 * (float)t4.x + (1.f - a4.x) * NEGV;
    o.y = slope2 * (float)t4.y + (1.f - a4.y) * NEGV;
    o.z = slope2 * (float)t4.z + (1.f - a4.z) * NEGV;
    o.w = slope2 * (float)t4.w + (1.f - a4.w) * NEGV;
    *(float4*)(colt_g + (size_t)((b * 16 + h) * S_LEN + k)) = o;
}

// -------------------- GEMM: C[M,N] = A[M,K] @ B[N,K]^T (bf16 in) --------------------
// FUSE_VT: epilogue writes V-transpose VT[bh][d][k] directly from acc; the V-region
//   C store is SKIPPED (attn reads V only via VT since the vt-fusion).
// HALF_N: BN=64 tile -> 2 blocks/CU for the small-N output GEMM.
// FUSE_NORM: A-staging applies groupnorm affine in-flight (reg-stage + ds_write).
//   Loads issued in a separate unrolled loop BEFORE the transform loop (T14-lite:
//   all 4 global loads in flight while the first is converted; identical math).
template<bool C_BF16, bool FUSE_VT, bool HALF_N, bool FUSE_NORM>
__global__ __launch_bounds__(256) void gemm_bt(const unsigned short* __restrict__ A,
                                               const unsigned short* __restrict__ B,
                                               void* __restrict__ C_,
                                               unsigned short* __restrict__ VT,
                                               const float* __restrict__ sum_ws,
                                               const float* __restrict__ sumsq_ws,
                                               const float* __restrict__ gamma,
                                               const float* __restrict__ beta,
                                               int M, int N, int K) {
    constexpr int BN = HALF_N ? 64 : 128;
    constexpr int NI = BN / 32;               // per-warp n-frags: 2 or 4
    const int m0 = blockIdx.y * 128;
    const int n0 = blockIdx.x * BN;
    __shared__ __align__(16) unsigned short As[128 * 64];
    __shared__ __align__(16) unsigned short Bs[BN * 64];
    const int tid  = threadIdx.x;
    const int lane = tid & 63;
    const int w    = tid >> 6;
    const int wm   = (w >> 1) * 64, wn = (w & 1) * (BN / 2);
    const int col  = lane & 15, quad = lane >> 4;

    f32x4 acc[4][NI] = {};

    const int srow = lane >> 3;
    const int gcol = ((lane & 7) ^ srow) * 8;

    [[maybe_unused]] float inv_n = 1.0f / (float)(S_LEN * 64);

    for (int k0 = 0; k0 < K; k0 += 64) {
        __syncthreads();
        const unsigned short* Ag = A + (size_t)m0 * K + k0 + gcol;
        const unsigned short* Bg = B + (size_t)n0 * K + k0 + gcol;
        if constexpr (FUSE_NORM) {
            // per-tile scalars: b uniform per block, h uniform per K-tile
            const int bi = (m0 >> 11) * 16 + (k0 >> 6);
            float mu = sum_ws[bi] * inv_n;
            float var = fmaxf(sumsq_ws[bi] * inv_n - mu * mu, 0.0f);
            float iv = rsqrtf(var + 1e-5f);
            const int c = k0 + gcol;                 // 8-aligned column base
            float4 g0 = *(const float4*)(gamma + c);
            float4 g1 = *(const float4*)(gamma + c + 4);
            float4 b0 = *(const float4*)(beta + c);
            float4 b1 = *(const float4*)(beta + c + 4);
            float gg[8] = { g0.x, g0.y, g0.z, g0.w, g1.x, g1.y, g1.z, g1.w };
            float bb8[8] = { b0.x, b0.y, b0.z, b0.w, b1.x, b1.y, b1.z, b1.w };
            ushort8 x8[4];
#pragma unroll
            for (int i = 0; i < 4; i++)
                x8[i] = *(const ushort8*)(Ag + (size_t)((w * 4 + i) * 8 + srow) * K);
#pragma unroll
            for (int i = 0; i < 4; i++) {
                const int blk = w * 4 + i;
                ushort8 t;
#pragma unroll
                for (int j = 0; j < 8; j++)
                    t[j] = f2bf(((bf2f(x8[i][j]) - mu) * iv * gg[j] + bb8[j]) * 0.2f);
                *(ushort8*)(As + blk * 512 + lane * 8) = t;   // same slot gld_lds16 used
            }
        } else {
#pragma unroll
            for (int i = 0; i < 4; i++) {
                const int blk = w * 4 + i;
                gld_lds16(Ag + (size_t)(blk * 8 + srow) * K, As + blk * 512);
            }
        }
#pragma unroll
        for (int i = 0; i < NI; i++) {
            const int blk = w * NI + i;
            gld_lds16(Bg + (size_t)(blk * 8 + srow) * K, Bs + blk * 512);
        }
        __syncthreads();

#pragma unroll
        for (int kk = 0; kk < 2; kk++) {
            const int swz = ((kk * 4 + quad) ^ (col & 7)) * 8;
            bf16x8 af[4], bb[NI];
#pragma unroll
            for (int mi = 0; mi < 4; mi++)
                af[mi] = *(const bf16x8*)(As + (wm + mi * 16 + col) * 64 + swz);
#pragma unroll
            for (int ni = 0; ni < NI; ni++)
                bb[ni] = *(const bf16x8*)(Bs + (wn + ni * 16 + col) * 64 + swz);
#pragma unroll
            for (int mi = 0; mi < 4; mi++)
#pragma unroll
                for (int ni = 0; ni < NI; ni++)
                    acc[mi][ni] = mfma32(af[mi], bb[ni], acc[mi][ni]);
        }
    }

#pragma unroll
    for (int mi = 0; mi < 4; mi++)
#pragma unroll
        for (int ni = 0; ni < NI; ni++) {
            const int row0 = m0 + wm + mi * 16 + quad * 4;
            const int cc   = n0 + wn + ni * 16 + col;
            if constexpr (FUSE_VT) {
                if (cc < 4096) {
#pragma unroll
                    for (int r = 0; r < 4; r++)
                        ((unsigned short*)C_)[(size_t)(row0 + r) * N + cc] = f2bf(acc[mi][ni][r]);
                } else {
                    // V column: vcol = h*64+d; VT[(b*16+h)*64+d][k], k = seq row
                    const int vcol = cc - 4096;
                    const int b    = row0 >> 11;
                    const int k    = row0 & 2047;       // 4 consecutive k
                    ushort4v t;
                    t.x = f2bf(acc[mi][ni][0]); t.y = f2bf(acc[mi][ni][1]);
                    t.z = f2bf(acc[mi][ni][2]); t.w = f2bf(acc[mi][ni][3]);
                    *(ushort4v*)(VT + ((size_t)(b * 16) * 64 + vcol) * 2048 + k) = t;
                }
            } else {
#pragma unroll
                for (int r = 0; r < 4; r++) {
                    if constexpr (C_BF16)
                        ((unsigned short*)C_)[(size_t)(row0 + r) * N + cc] = f2bf(acc[mi][ni][r]);
                    else
                        ((float*)C_)[(size_t)(row0 + r) * N + cc] = acc[mi][ni][r];
                }
            }
        }
}

// -------------------- differential flash attention (8-warp, balanced pair split) ----
// Verbatim the r11/r13 kernel (verified best: 106-108 us). Pair-batched tile():
// QK^T for two mts (interleaved MFMA chains), both softmaxes in parallel, then both
// PV streams. VALU l-sums + shfl reduction (r14's ones-MFMA was neutral with +12MB
// spill -> reverted). setprio / softmax-serialization / complementary-pair all
// measured negative in r8/r12 and stay out.
__global__ __launch_bounds__(512, 4) void attn_kernel(
    const unsigned short* __restrict__ QKV, const unsigned short* __restrict__ VT,
    const int* __restrict__ tok, const float* __restrict__ colt_g,
    const float* __restrict__ lam_ws, unsigned short* __restrict__ attnb,
    float* __restrict__ sum_ws, float* __restrict__ sumsq_ws)
{
    const int bid  = blockIdx.x;
    const int xcd  = bid & 7;
    const int tt   = bid >> 3;
    const int pair = tt & 15;
    const int bh   = (tt >> 4) * 8 + xcd;   // all blocks of a bh share one XCD
    const int b = bh >> 4, h = bh & 15;
    const int tid = threadIdx.x, lane = tid & 63, w = tid >> 6;
    const int wq = w & 3, side = w >> 2;    // side 0 = light owner, 1 = heavy owner
    const int col = lane & 15, quad = lane >> 4;
    const int qtH = 31 - pair;
    const int kmax = qtH;                   // >= 16 > pair always

    __shared__ __align__(16) unsigned short SMEM[24576];  // 48KB
    unsigned short* Kb = SMEM;           // [buf*8192]: K1 (4096) | K2 (4096)
    unsigned short* Vb = SMEM + 16384;   // [buf*4096]: VT tile, swizzled

    const float LOG2E = 1.44269504f;
    const float slope2 = exp2f(-0.5f * (float)(h + 1)) * LOG2E;
    const float scale2 = 0.125f * LOG2E;
    const float* cg = colt_g + (size_t)bh * S_LEN;

    const int srow  = lane >> 3;
    const int kgcol = ((lane & 7) ^ srow) * 8;     // swizzled 16B group
    const int srow8 = w * 8 + srow;                // wave w stages rows w*8..w*8+7
    const unsigned short* kbase  = QKV + (size_t)(b * S_LEN) * QKV_STRIDE + 2048 + h * 128 + kgcol;
    const unsigned short* vtbase = VT + (size_t)bh * 131072 + kgcol;

    auto stage = [&](int kt, int bf) {
        const unsigned short* kg = kbase + (size_t)(kt * 64 + srow8) * QKV_STRIDE;
        gld_lds16(kg,      Kb + bf * 8192 + w * 512);
        gld_lds16(kg + 64, Kb + bf * 8192 + 4096 + w * 512);
        gld_lds16(vtbase + (size_t)srow8 * 2048 + kt * 64, Vb + bf * 4096 + w * 512);
    };

    int qidx = (side ? qtH : pair) * 64 + wq * 16 + col;
    const unsigned short* qp = QKV + (size_t)(b * S_LEN + qidx) * QKV_STRIDE + h * 128;
    bf16x8 q1f0 = *(const bf16x8*)(qp + quad * 8);
    bf16x8 q1f1 = *(const bf16x8*)(qp + 32 + quad * 8);
    bf16x8 q2f0 = *(const bf16x8*)(qp + 64 + quad * 8);
    bf16x8 q2f1 = *(const bf16x8*)(qp + 96 + quad * 8);
    float rowt = -slope2 * (float)tok[b * S_LEN + qidx];
    const float lam = lam_ws[0];

    float l1 = 0.f, l2 = 0.f, s = 0.f, ss = 0.f;
    f32x4 O1[4] = {}, O2[4] = {};

    stage(0, 0);

    auto tile = [&](int kt, auto mt0C, auto mtnC, auto causalC) {
        constexpr int  MT0    = decltype(mt0C)::value;
        constexpr int  MTN    = decltype(mtnC)::value;
        constexpr bool CAUSAL = decltype(causalC)::value;
        const int cur = kt & 1;
        const int k0 = kt * 64;
        const unsigned short* K1s = Kb + cur * 8192;
        const unsigned short* K2s = K1s + 4096;
        const unsigned short* Vs  = Vb + cur * 4096;
        const int sw0 = (quad ^ (col & 7)) * 8;
        const int sw1 = ((4 + quad) ^ (col & 7)) * 8;
#pragma unroll
        for (int ib = 0; ib < MTN; ib += 2) {
            const int mta = MT0 + ib, mtb = MT0 + ib + 1;
            const unsigned short* kr1a = K1s + (mta * 16 + col) * 64;
            const unsigned short* kr2a = K2s + (mta * 16 + col) * 64;
            const unsigned short* kr1b = K1s + (mtb * 16 + col) * 64;
            const unsigned short* kr2b = K2s + (mtb * 16 + col) * 64;
            // phase 1: QK^T for both mts (interleaved independent chains)
            f32x4 s1a = {}, s2a = {}, s1b = {}, s2b = {};
            s1a = mfma32(*(const bf16x8*)(kr1a + sw0), q1f0, s1a);
            s1b = mfma32(*(const bf16x8*)(kr1b + sw0), q1f0, s1b);
            s2a = mfma32(*(const bf16x8*)(kr2a + sw0), q2f0, s2a);
            s2b = mfma32(*(const bf16x8*)(kr2b + sw0), q2f0, s2b);
            s1a = mfma32(*(const bf16x8*)(kr1a + sw1), q1f1, s1a);
            s1b = mfma32(*(const bf16x8*)(kr1b + sw1), q1f1, s1b);
            s2a = mfma32(*(const bf16x8*)(kr2a + sw1), q2f1, s2a);
            s2b = mfma32(*(const bf16x8*)(kr2b + sw1), q2f1, s2b);
            // phase 2: softmax for both (independent TRANS streams)
            float4 cta = *(const float4*)(cg + k0 + mta * 16 + quad * 4);
            float4 ctb = *(const float4*)(cg + k0 + mtb * 16 + quad * 4);
            float pa[4], ra[4], pb[4], rb[4];
#pragma unroll
            for (int r = 0; r < 4; r++) {
                float basea = rowt + (&cta.x)[r];
                float baseb = rowt + (&ctb.x)[r];
                if constexpr (CAUSAL) {
                    int keya = k0 + mta * 16 + quad * 4 + r;
                    int keyb = k0 + mtb * 16 + quad * 4 + r;
                    basea = (keya > qidx) ? -1e9f : basea;
                    baseb = (keyb > qidx) ? -1e9f : baseb;
                }
                pa[r] = exp2f(s1a[r] * scale2 + basea);
                ra[r] = exp2f(s2a[r] * scale2 + basea);
                pb[r] = exp2f(s1b[r] * scale2 + baseb);
                rb[r] = exp2f(s2b[r] * scale2 + baseb);
            }
            l1 += (pa[0] + pa[1]) + (pa[2] + pa[3]);
            l2 += (ra[0] + ra[1]) + (ra[2] + ra[3]);
            l1 += (pb[0] + pb[1]) + (pb[2] + pb[3]);
            l2 += (rb[0] + rb[1]) + (rb[2] + rb[3]);
            uint2v u1a; u1a.x = pk2bf(pa[0], pa[1]); u1a.y = pk2bf(pa[2], pa[3]);
            uint2v u2a; u2a.x = pk2bf(ra[0], ra[1]); u2a.y = pk2bf(ra[2], ra[3]);
            uint2v u1b; u1b.x = pk2bf(pb[0], pb[1]); u1b.y = pk2bf(pb[2], pb[3]);
            uint2v u2b; u2b.x = pk2bf(rb[0], rb[1]); u2b.y = pk2bf(rb[2], rb[3]);
            ushort4v pf1a = __builtin_bit_cast(ushort4v, u1a);
            ushort4v pf2a = __builtin_bit_cast(ushort4v, u2a);
            ushort4v pf1b = __builtin_bit_cast(ushort4v, u1b);
            ushort4v pf2b = __builtin_bit_cast(ushort4v, u2b);
            // phase 3: PV for both (a before b on each O: same accum order as serial)
            const int voffa = ((mta * 2 + (quad >> 1)) ^ (col & 7)) * 8 + (quad & 1) * 4;
            const int voffb = ((mtb * 2 + (quad >> 1)) ^ (col & 7)) * 8 + (quad & 1) * 4;
#pragma unroll
            for (int dt = 0; dt < 4; dt++) {
                ushort4v vfa = *(const ushort4v*)(Vs + (dt * 16 + col) * 64 + voffa);
                ushort4v vfb = *(const ushort4v*)(Vs + (dt * 16 + col) * 64 + voffb);
                O1[dt] = mfma16(vfa, pf1a, O1[dt]);
                O2[dt] = mfma16(vfa, pf2a, O2[dt]);
                O1[dt] = mfma16(vfb, pf1b, O1[dt]);
                O2[dt] = mfma16(vfb, pf2b, O2[dt]);
            }
        }
    };

    auto finalize = [&]() {
        l1 += __shfl_xor(l1, 16); l1 += __shfl_xor(l1, 32);
        l2 += __shfl_xor(l2, 16); l2 += __shfl_xor(l2, 32);
        const float il1 = 1.0f / l1, il2 = lam / l2;
        unsigned short* op = attnb + (size_t)(b * S_LEN + qidx) * 1024 + h * 64;
#pragma unroll
        for (int dt = 0; dt < 4; dt++) {
            f32x4 o = O1[dt] * il1 - O2[dt] * il2;
            ushort4v t;
            t.x = f2bf(o[0]); t.y = f2bf(o[1]); t.z = f2bf(o[2]); t.w = f2bf(o[3]);
            *(ushort4v*)(op + dt * 16 + quad * 4) = t;
            s  += (o[0] + o[1]) + (o[2] + o[3]);
            ss += (o[0]*o[0] + o[1]*o[1]) + (o[2]*o[2] + o[3]*o[3]);
        }
    };

    // ---- shared phase: kt = 0 .. pair-1 (both sides, full tile, non-causal) ----
    for (int kt = 0; kt < pair; kt++) {
        __syncthreads();
        stage(kt + 1, (kt + 1) & 1);
        tile(kt, IntC<0>{}, IntC<4>{}, BoolC<false>{});
    }
    // ---- kt = pair: light diagonal (causal for side 0 only) ----
    {
        __syncthreads();
        stage(pair + 1, (pair + 1) & 1);       // pair+1 <= kmax always
        if (!side) tile(pair, IntC<0>{}, IntC<4>{}, BoolC<true>{});
        else       tile(pair, IntC<0>{}, IntC<4>{}, BoolC<false>{});
    }
    // ---- top-level phase switch: finalize light tile, swap to heavy rows ----
    if (!side) {
        finalize();
        f32x4 zero = {};
#pragma unroll
        for (int dt = 0; dt < 4; dt++) { O1[dt] = zero; O2[dt] = zero; }
        l1 = 0.f; l2 = 0.f;
        qidx = qtH * 64 + wq * 16 + col;
        const unsigned short* qh = QKV + (size_t)(b * S_LEN + qidx) * QKV_STRIDE + h * 128;
        q1f0 = *(const bf16x8*)(qh + quad * 8);
        q1f1 = *(const bf16x8*)(qh + 32 + quad * 8);
        q2f0 = *(const bf16x8*)(qh + 64 + quad * 8);
        q2f1 = *(const bf16x8*)(qh + 96 + quad * 8);
        rowt = -slope2 * (float)tok[b * S_LEN + qidx];
    }
    // ---- tail: kt = pair+1 .. kmax-1 (heavy only, key-split halves) ----
    for (int kt = pair + 1; kt < kmax; kt++) {
        __syncthreads();
        stage(kt + 1, (kt + 1) & 1);
        if (side) tile(kt, IntC<0>{}, IntC<2>{}, BoolC<false>{});
        else      tile(kt, IntC<2>{}, IntC<2>{}, BoolC<false>{});
    }
    // ---- kt = kmax: heavy diagonal (causal, key-split halves) ----
    {
        __syncthreads();
        if (side) tile(kmax, IntC<0>{}, IntC<2>{}, BoolC<true>{});
        else      tile(kmax, IntC<2>{}, IntC<2>{}, BoolC<true>{});
    }

    // combine tail partials: warps 0-3 -> warps 4-7 (same q-slice wq)
    __syncthreads();                           // last tile's LDS reads done
    float* comb = (float*)SMEM;
    if (!side) {
        float* p = comb + (size_t)(w * 64 + lane) * 36;
#pragma unroll
        for (int dt = 0; dt < 4; dt++) {
            *(f32x4*)(p + dt * 4)      = O1[dt];
            *(f32x4*)(p + 16 + dt * 4) = O2[dt];
        }
        p[32] = l1; p[33] = l2;
    }
    __syncthreads();
    if (side) {
        const float* p = comb + (size_t)((w - 4) * 64 + lane) * 36;
#pragma unroll
        for (int dt = 0; dt < 4; dt++) {
            O1[dt] += *(const f32x4*)(p + dt * 4);
            O2[dt] += *(const f32x4*)(p + 16 + dt * 4);
        }
        l1 += p[32]; l2 += p[33];
        finalize();                            // heavy tile -> store it
    }

    for (int off = 1; off < 64; off <<= 1) { s += __shfl_xor(s, off); ss += __shfl_xor(ss, off); }
    if (lane == 0) {
        atomicAdd(&sum_ws[bh], s);
        atomicAdd(&sumsq_ws[bh], ss);
    }
}

// -------------------- launch --------------------
extern "C" void kernel_launch(void* const* d_in, const int* in_sizes, int n_in,
                              void* d_out, int out_size, void* d_ws, size_t ws_size,
                              hipStream_t stream) {
    const float* inputs = (const float*)d_in[0];
    const float* amask  = (const float*)d_in[1];
    const int*   tok    = (const int*)d_in[2];
    const float* Wq     = (const float*)d_in[3];
    const float* Wk     = (const float*)d_in[4];
    const float* Wv     = (const float*)d_in[5];
    const float* Wo     = (const float*)d_in[6];
    const float* lq1    = (const float*)d_in[7];
    const float* lq2    = (const float*)d_in[8];
    const float* lk1    = (const float*)d_in[9];
    const float* lk2    = (const float*)d_in[10];
    const float* gamma  = (const float*)d_in[11];
    const float* beta   = (const float*)d_in[12];
    float* out = (float*)d_out;

    char* ws = (char*)d_ws;
    float* lam_ws   = (float*)ws;
    float* sum_ws   = (float*)(ws + 256);
    float* sumsq_ws = (float*)(ws + 512);
    float* colt_g   = (float*)(ws + 1024);          // 65536 floats = 256 KB
    unsigned short* Wob   = (unsigned short*)(ws + 1024 + 262144);
    unsigned short* QKVb  = Wob + 1048576;          // 4096 x 5120
    unsigned short* Xb    = QKVb + 20971520;        // 4096 x 1024
    unsigned short* Wqkvb = Xb + 4194304;           // 5120 x 1024
    unsigned short* VTb   = Wqkvb + 5242880;        // 32 x 64 x 2048
    unsigned short* attnb = Xb;                     // alias (X dead after QKV GEMM)

    cvt5lam_kernel<<<10304, 256, 0, stream>>>(inputs, Wq, Wk, Wv, Wo, Xb, Wqkvb, Wob,
                                              lq1, lk1, lq2, lk2, tok, amask,
                                              lam_ws, sum_ws, sumsq_ws, colt_g);
    gemm_bt<true, true, false, false><<<dim3(40, 32), 256, 0, stream>>>(
        Xb, Wqkvb, QKVb, VTb, nullptr, nullptr, nullptr, nullptr, 4096, 5120, 1024);
    attn_kernel<<<512, 512, 0, stream>>>(QKVb, VTb, tok, colt_g, lam_ws,
                                         attnb, sum_ws, sumsq_ws);
    gemm_bt<false, false, true, true><<<dim3(16, 32), 256, 0, stream>>>(
        attnb, Wob, out, nullptr, sum_ws, sumsq_ws, gamma, beta, 4096, 1024, 1024);
}

// Round 16
// 278.620 us; speedup vs baseline: 1.0139x; 1.0139x over previous
//
#include <hip/hip_runtime.h>
#include <hip/hip_bf16.h>
#include <cstdint>
#include <cstddef>

#define S_LEN 2048
#define NEGV -1e9f
#define QKV_STRIDE 5120

using bf16x8   = __attribute__((ext_vector_type(8))) __bf16;
using bf16x4   = __attribute__((ext_vector_type(4))) __bf16;
using ushort8  = __attribute__((ext_vector_type(8))) unsigned short;
using ushort4v = __attribute__((ext_vector_type(4))) unsigned short;
using f32x4    = __attribute__((ext_vector_type(4))) float;
using uint2v   = __attribute__((ext_vector_type(2))) unsigned int;

template<bool V> struct BoolC { static constexpr bool value = V; };
template<int V>  struct IntC  { static constexpr int  value = V; };

__device__ __forceinline__ unsigned short f2bf(float f) {
    union { float f; unsigned u; } v; v.f = f;
    unsigned u = v.u;
    return (unsigned short)((u + 0x7fffu + ((u >> 16) & 1u)) >> 16);
}

__device__ __forceinline__ float bf2f(unsigned short u) {
    union { unsigned u; float f; } cv; cv.u = (unsigned)u << 16;
    return cv.f;
}

// pack two positive floats -> {bf16(b),bf16(a)} with round-half-up via v_perm
__device__ __forceinline__ unsigned pk2bf(float a, float b) {
    unsigned ua = __builtin_bit_cast(unsigned, a) + 0x8000u;
    unsigned ub = __builtin_bit_cast(unsigned, b) + 0x8000u;
    return __builtin_amdgcn_perm(ub, ua, 0x07060302u);
}

__device__ __forceinline__ void gld_lds16(const unsigned short* g, unsigned short* l) {
    __builtin_amdgcn_global_load_lds(
        (const __attribute__((address_space(1))) void*)(g),
        (__attribute__((address_space(3))) void*)(l), 16, 0, 0);
}

__device__ __forceinline__ f32x4 mfma32(bf16x8 a, bf16x8 b, f32x4 c) {
    return __builtin_amdgcn_mfma_f32_16x16x32_bf16(a, b, c, 0, 0, 0);
}

__device__ __forceinline__ f32x4 mfma16(ushort4v a, ushort4v b, f32x4 c) {
#if __has_builtin(__builtin_amdgcn_mfma_f32_16x16x16_bf16)
    return __builtin_amdgcn_mfma_f32_16x16x16_bf16(
        __builtin_bit_cast(bf16x4, a), __builtin_bit_cast(bf16x4, b), c, 0, 0, 0);
#else
    return __builtin_amdgcn_mfma_f32_16x16x16bf16_1k(
        __builtin_bit_cast(bf16x4, a), __builtin_bit_cast(bf16x4, b), c, 0, 0, 0);
#endif
}

// ------------- fused fp32->bf16 convert (blocks 0..10239) + lamcolt (blocks 10240+) -
__global__ __launch_bounds__(256) void cvt5lam_kernel(
    const float* __restrict__ X,  const float* __restrict__ Wq,
    const float* __restrict__ Wk, const float* __restrict__ Wv,
    const float* __restrict__ Wo,
    unsigned short* __restrict__ Xb, unsigned short* __restrict__ Wqkvb,
    unsigned short* __restrict__ Wob,
    const float* __restrict__ lq1, const float* __restrict__ lk1,
    const float* __restrict__ lq2, const float* __restrict__ lk2,
    const int* __restrict__ tok, const float* __restrict__ amask,
    float* __restrict__ lam_ws, float* __restrict__ sum_ws,
    float* __restrict__ sumsq_ws, float* __restrict__ colt_g) {
    if (blockIdx.x < 10240) {
        int i = blockIdx.x * 256 + threadIdx.x;   // float4 index, total 2621440
        const float* src; unsigned short* dst; int off;
        if      (i < 1048576) { src = X;  dst = Xb;              off = 0;       }
        else if (i < 1572864) { src = Wq; dst = Wqkvb;           off = 1048576; }
        else if (i < 2097152) { src = Wk; dst = Wqkvb + 2097152; off = 1572864; }
        else if (i < 2359296) { src = Wv; dst = Wqkvb + 4194304; off = 2097152; }
        else                  { src = Wo; dst = Wob;             off = 2359296; }
        int j = i - off;
        float4 v = ((const float4*)src)[j];
        ushort4v t;
        t.x = f2bf(v.x); t.y = f2bf(v.y); t.z = f2bf(v.z); t.w = f2bf(v.w);
        ((ushort4v*)dst)[j] = t;
        return;
    }
    const int bid2 = blockIdx.x - 10240;          // 0..63: lamcolt part
    const int gid = bid2 * 256 + threadIdx.x;
    if (bid2 == 0) {
        int t = threadIdx.x;
        if (t >= 64 && t < 96)  sum_ws[t - 64] = 0.f;
        if (t >= 96 && t < 128) sumsq_ws[t - 96] = 0.f;
        if (t < 64) {
            float a = lq1[t] * lk1[t];
            float b = lq2[t] * lk2[t];
            for (int off = 32; off > 0; off >>= 1) {
                a += __shfl_xor(a, off);
                b += __shfl_xor(b, off);
            }
            if (t == 0) lam_ws[0] = __expf(a) - __expf(b) + 0.8f;
        }
    }
    const int b = gid >> 13, h = (gid >> 9) & 15, k = (gid & 511) * 4;
    const float slope2 = exp2f(-0.5f * (float)(h + 1)) * 1.44269504f;
    int4   t4 = *(const int4*)(tok + b * S_LEN + k);
    float4 a4 = *(const float4*)(amask + b * S_LEN + k);
    float4 o;
    o.x = slope2 * (float)t4.x + (1.f - a4.x) * NEGV;
    o.y = slope2 * (float)t4.y + (1.f - a4.y) * NEGV;
    o.z = slope2 * (float)t4.z + (1.f - a4.z) * NEGV;
    o.w = slope2 * (float)t4.w + (1.f - a4.w) * NEGV;
    *(float4*)(colt_g + (size_t)((b * 16 + h) * S_LEN + k)) = o;
}

// -------------------- GEMM: C[M,N] = A[M,K] @ B[N,K]^T (bf16 in) --------------------
// FUSE_VT: epilogue writes V-transpose VT[bh][d][k] directly from acc; the V-region
//   C store is SKIPPED (attn reads V only via VT since the vt-fusion).
// HALF_N: BN=64 tile -> 2 blocks/CU for the small-N output GEMM.
// FUSE_NORM: A-staging applies groupnorm affine in-flight (reg-stage + ds_write).
// SWZ1D: 1D grid with XCD-chunked decode -- each XCD owns N/128/8 consecutive
//   n-panels (for gemm1: 5 panels x 256KB = 1.25MB of B -> per-XCD L2-resident;
//   converts ~300MB of cross-XCD L3 B-reads into L2 hits). Bijective: 1280 = 8x160.
template<bool C_BF16, bool FUSE_VT, bool HALF_N, bool FUSE_NORM, bool SWZ1D>
__global__ __launch_bounds__(256) void gemm_bt(const unsigned short* __restrict__ A,
                                               const unsigned short* __restrict__ B,
                                               void* __restrict__ C_,
                                               unsigned short* __restrict__ VT,
                                               const float* __restrict__ sum_ws,
                                               const float* __restrict__ sumsq_ws,
                                               const float* __restrict__ gamma,
                                               const float* __restrict__ beta,
                                               int M, int N, int K) {
    constexpr int BN = HALF_N ? 64 : 128;
    constexpr int NI = BN / 32;               // per-warp n-frags: 2 or 4
    int m0, n0;
    if constexpr (SWZ1D) {
        const int bid = blockIdx.x;
        const int xcd = bid & 7;
        const int t   = bid >> 3;             // 0 .. nwg/8-1
        const int NC  = N / BN / 8;           // n-panels per XCD (gemm1: 5)
        n0 = (xcd * NC + (t % NC)) * BN;
        m0 = (t / NC) * 128;
    } else {
        m0 = blockIdx.y * 128;
        n0 = blockIdx.x * BN;
    }
    __shared__ __align__(16) unsigned short As[128 * 64];
    __shared__ __align__(16) unsigned short Bs[BN * 64];
    const int tid  = threadIdx.x;
    const int lane = tid & 63;
    const int w    = tid >> 6;
    const int wm   = (w >> 1) * 64, wn = (w & 1) * (BN / 2);
    const int col  = lane & 15, quad = lane >> 4;

    f32x4 acc[4][NI] = {};

    const int srow = lane >> 3;
    const int gcol = ((lane & 7) ^ srow) * 8;

    [[maybe_unused]] float inv_n = 1.0f / (float)(S_LEN * 64);

    for (int k0 = 0; k0 < K; k0 += 64) {
        __syncthreads();
        const unsigned short* Ag = A + (size_t)m0 * K + k0 + gcol;
        const unsigned short* Bg = B + (size_t)n0 * K + k0 + gcol;
        if constexpr (FUSE_NORM) {
            // per-tile scalars: b uniform per block, h uniform per K-tile
            const int bi = (m0 >> 11) * 16 + (k0 >> 6);
            float mu = sum_ws[bi] * inv_n;
            float var = fmaxf(sumsq_ws[bi] * inv_n - mu * mu, 0.0f);
            float iv = rsqrtf(var + 1e-5f);
            const int c = k0 + gcol;                 // 8-aligned column base
            float4 g0 = *(const float4*)(gamma + c);
            float4 g1 = *(const float4*)(gamma + c + 4);
            float4 b0 = *(const float4*)(beta + c);
            float4 b1 = *(const float4*)(beta + c + 4);
            float gg[8] = { g0.x, g0.y, g0.z, g0.w, g1.x, g1.y, g1.z, g1.w };
            float bb8[8] = { b0.x, b0.y, b0.z, b0.w, b1.x, b1.y, b1.z, b1.w };
            ushort8 x8[4];
#pragma unroll
            for (int i = 0; i < 4; i++)
                x8[i] = *(const ushort8*)(Ag + (size_t)((w * 4 + i) * 8 + srow) * K);
#pragma unroll
            for (int i = 0; i < 4; i++) {
                const int blk = w * 4 + i;
                ushort8 t;
#pragma unroll
                for (int j = 0; j < 8; j++)
                    t[j] = f2bf(((bf2f(x8[i][j]) - mu) * iv * gg[j] + bb8[j]) * 0.2f);
                *(ushort8*)(As + blk * 512 + lane * 8) = t;   // same slot gld_lds16 used
            }
        } else {
#pragma unroll
            for (int i = 0; i < 4; i++) {
                const int blk = w * 4 + i;
                gld_lds16(Ag + (size_t)(blk * 8 + srow) * K, As + blk * 512);
            }
        }
#pragma unroll
        for (int i = 0; i < NI; i++) {
            const int blk = w * NI + i;
            gld_lds16(Bg + (size_t)(blk * 8 + srow) * K, Bs + blk * 512);
        }
        __syncthreads();

#pragma unroll
        for (int kk = 0; kk < 2; kk++) {
            const int swz = ((kk * 4 + quad) ^ (col & 7)) * 8;
            bf16x8 af[4], bb[NI];
#pragma unroll
            for (int mi = 0; mi < 4; mi++)
                af[mi] = *(const bf16x8*)(As + (wm + mi * 16 + col) * 64 + swz);
#pragma unroll
            for (int ni = 0; ni < NI; ni++)
                bb[ni] = *(const bf16x8*)(Bs + (wn + ni * 16 + col) * 64 + swz);
#pragma unroll
            for (int mi = 0; mi < 4; mi++)
#pragma unroll
                for (int ni = 0; ni < NI; ni++)
                    acc[mi][ni] = mfma32(af[mi], bb[ni], acc[mi][ni]);
        }
    }

#pragma unroll
    for (int mi = 0; mi < 4; mi++)
#pragma unroll
        for (int ni = 0; ni < NI; ni++) {
            const int row0 = m0 + wm + mi * 16 + quad * 4;
            const int cc   = n0 + wn + ni * 16 + col;
            if constexpr (FUSE_VT) {
                if (cc < 4096) {
#pragma unroll
                    for (int r = 0; r < 4; r++)
                        ((unsigned short*)C_)[(size_t)(row0 + r) * N + cc] = f2bf(acc[mi][ni][r]);
                } else {
                    // V column: vcol = h*64+d; VT[(b*16+h)*64+d][k], k = seq row
                    const int vcol = cc - 4096;
                    const int b    = row0 >> 11;
                    const int k    = row0 & 2047;       // 4 consecutive k
                    ushort4v t;
                    t.x = f2bf(acc[mi][ni][0]); t.y = f2bf(acc[mi][ni][1]);
                    t.z = f2bf(acc[mi][ni][2]); t.w = f2bf(acc[mi][ni][3]);
                    *(ushort4v*)(VT + ((size_t)(b * 16) * 64 + vcol) * 2048 + k) = t;
                }
            } else {
#pragma unroll
                for (int r = 0; r < 4; r++) {
                    if constexpr (C_BF16)
                        ((unsigned short*)C_)[(size_t)(row0 + r) * N + cc] = f2bf(acc[mi][ni][r]);
                    else
                        ((float*)C_)[(size_t)(row0 + r) * N + cc] = acc[mi][ni][r];
                }
            }
        }
}

// -------------------- differential flash attention (8-warp, balanced pair split) ----
// Verbatim the r11/r13/r15 kernel (verified best: 106-108 us). Pair-batched tile():
// QK^T for two mts (interleaved MFMA chains), both softmaxes in parallel, then both
// PV streams. VALU l-sums + shfl reduction.
__global__ __launch_bounds__(512, 4) void attn_kernel(
    const unsigned short* __restrict__ QKV, const unsigned short* __restrict__ VT,
    const int* __restrict__ tok, const float* __restrict__ colt_g,
    const float* __restrict__ lam_ws, unsigned short* __restrict__ attnb,
    float* __restrict__ sum_ws, float* __restrict__ sumsq_ws)
{
    const int bid  = blockIdx.x;
    const int xcd  = bid & 7;
    const int tt   = bid >> 3;
    const int pair = tt & 15;
    const int bh   = (tt >> 4) * 8 + xcd;   // all blocks of a bh share one XCD
    const int b = bh >> 4, h = bh & 15;
    const int tid = threadIdx.x, lane = tid & 63, w = tid >> 6;
    const int wq = w & 3, side = w >> 2;    // side 0 = light owner, 1 = heavy owner
    const int col = lane & 15, quad = lane >> 4;
    const int qtH = 31 - pair;
    const int kmax = qtH;                   // >= 16 > pair always

    __shared__ __align__(16) unsigned short SMEM[24576];  // 48KB
    unsigned short* Kb = SMEM;           // [buf*8192]: K1 (4096) | K2 (4096)
    unsigned short* Vb = SMEM + 16384;   // [buf*4096]: VT tile, swizzled

    const float LOG2E = 1.44269504f;
    const float slope2 = exp2f(-0.5f * (float)(h + 1)) * LOG2E;
    const float scale2 = 0.125f * LOG2E;
    const float* cg = colt_g + (size_t)bh * S_LEN;

    const int srow  = lane >> 3;
    const int kgcol = ((lane & 7) ^ srow) * 8;     // swizzled 16B group
    const int srow8 = w * 8 + srow;                // wave w stages rows w*8..w*8+7
    const unsigned short* kbase  = QKV + (size_t)(b * S_LEN) * QKV_STRIDE + 2048 + h * 128 + kgcol;
    const unsigned short* vtbase = VT + (size_t)bh * 131072 + kgcol;

    auto stage = [&](int kt, int bf) {
        const unsigned short* kg = kbase + (size_t)(kt * 64 + srow8) * QKV_STRIDE;
        gld_lds16(kg,      Kb + bf * 8192 + w * 512);
        gld_lds16(kg + 64, Kb + bf * 8192 + 4096 + w * 512);
        gld_lds16(vtbase + (size_t)srow8 * 2048 + kt * 64, Vb + bf * 4096 + w * 512);
    };

    int qidx = (side ? qtH : pair) * 64 + wq * 16 + col;
    const unsigned short* qp = QKV + (size_t)(b * S_LEN + qidx) * QKV_STRIDE + h * 128;
    bf16x8 q1f0 = *(const bf16x8*)(qp + quad * 8);
    bf16x8 q1f1 = *(const bf16x8*)(qp + 32 + quad * 8);
    bf16x8 q2f0 = *(const bf16x8*)(qp + 64 + quad * 8);
    bf16x8 q2f1 = *(const bf16x8*)(qp + 96 + quad * 8);
    float rowt = -slope2 * (float)tok[b * S_LEN + qidx];
    const float lam = lam_ws[0];

    float l1 = 0.f, l2 = 0.f, s = 0.f, ss = 0.f;
    f32x4 O1[4] = {}, O2[4] = {};

    stage(0, 0);

    auto tile = [&](int kt, auto mt0C, auto mtnC, auto causalC) {
        constexpr int  MT0    = decltype(mt0C)::value;
        constexpr int  MTN    = decltype(mtnC)::value;
        constexpr bool CAUSAL = decltype(causalC)::value;
        const int cur = kt & 1;
        const int k0 = kt * 64;
        const unsigned short* K1s = Kb + cur * 8192;
        const unsigned short* K2s = K1s + 4096;
        const unsigned short* Vs  = Vb + cur * 4096;
        const int sw0 = (quad ^ (col & 7)) * 8;
        const int sw1 = ((4 + quad) ^ (col & 7)) * 8;
#pragma unroll
        for (int ib = 0; ib < MTN; ib += 2) {
            const int mta = MT0 + ib, mtb = MT0 + ib + 1;
            const unsigned short* kr1a = K1s + (mta * 16 + col) * 64;
            const unsigned short* kr2a = K2s + (mta * 16 + col) * 64;
            const unsigned short* kr1b = K1s + (mtb * 16 + col) * 64;
            const unsigned short* kr2b = K2s + (mtb * 16 + col) * 64;
            // phase 1: QK^T for both mts (interleaved independent chains)
            f32x4 s1a = {}, s2a = {}, s1b = {}, s2b = {};
            s1a = mfma32(*(const bf16x8*)(kr1a + sw0), q1f0, s1a);
            s1b = mfma32(*(const bf16x8*)(kr1b + sw0), q1f0, s1b);
            s2a = mfma32(*(const bf16x8*)(kr2a + sw0), q2f0, s2a);
            s2b = mfma32(*(const bf16x8*)(kr2b + sw0), q2f0, s2b);
            s1a = mfma32(*(const bf16x8*)(kr1a + sw1), q1f1, s1a);
            s1b = mfma32(*(const bf16x8*)(kr1b + sw1), q1f1, s1b);
            s2a = mfma32(*(const bf16x8*)(kr2a + sw1), q2f1, s2a);
            s2b = mfma32(*(const bf16x8*)(kr2b + sw1), q2f1, s2b);
            // phase 2: softmax for both (independent TRANS streams)
            float4 cta = *(const float4*)(cg + k0 + mta * 16 + quad * 4);
            float4 ctb = *(const float4*)(cg + k0 + mtb * 16 + quad * 4);
            float pa[4], ra[4], pb[4], rb[4];
#pragma unroll
            for (int r = 0; r < 4; r++) {
                float basea = rowt + (&cta.x)[r];
                float baseb = rowt + (&ctb.x)[r];
                if constexpr (CAUSAL) {
                    int keya = k0 + mta * 16 + quad * 4 + r;
                    int keyb = k0 + mtb * 16 + quad * 4 + r;
                    basea = (keya > qidx) ? -1e9f : basea;
                    baseb = (keyb > qidx) ? -1e9f : baseb;
                }
                pa[r] = exp2f(s1a[r] * scale2 + basea);
                ra[r] = exp2f(s2a[r] * scale2 + basea);
                pb[r] = exp2f(s1b[r] * scale2 + baseb);
                rb[r] = exp2f(s2b[r] * scale2 + baseb);
            }
            l1 += (pa[0] + pa[1]) + (pa[2] + pa[3]);
            l2 += (ra[0] + ra[1]) + (ra[2] + ra[3]);
            l1 += (pb[0] + pb[1]) + (pb[2] + pb[3]);
            l2 += (rb[0] + rb[1]) + (rb[2] + rb[3]);
            uint2v u1a; u1a.x = pk2bf(pa[0], pa[1]); u1a.y = pk2bf(pa[2], pa[3]);
            uint2v u2a; u2a.x = pk2bf(ra[0], ra[1]); u2a.y = pk2bf(ra[2], ra[3]);
            uint2v u1b; u1b.x = pk2bf(pb[0], pb[1]); u1b.y = pk2bf(pb[2], pb[3]);
            uint2v u2b; u2b.x = pk2bf(rb[0], rb[1]); u2b.y = pk2bf(rb[2], rb[3]);
            ushort4v pf1a = __builtin_bit_cast(ushort4v, u1a);
            ushort4v pf2a = __builtin_bit_cast(ushort4v, u2a);
            ushort4v pf1b = __builtin_bit_cast(ushort4v, u1b);
            ushort4v pf2b = __builtin_bit_cast(ushort4v, u2b);
            // phase 3: PV for both (a before b on each O: same accum order as serial)
            const int voffa = ((mta * 2 + (quad >> 1)) ^ (col & 7)) * 8 + (quad & 1) * 4;
            const int voffb = ((mtb * 2 + (quad >> 1)) ^ (col & 7)) * 8 + (quad & 1) * 4;
#pragma unroll
            for (int dt = 0; dt < 4; dt++) {
                ushort4v vfa = *(const ushort4v*)(Vs + (dt * 16 + col) * 64 + voffa);
                ushort4v vfb = *(const ushort4v*)(Vs + (dt * 16 + col) * 64 + voffb);
                O1[dt] = mfma16(vfa, pf1a, O1[dt]);
                O2[dt] = mfma16(vfa, pf2a, O2[dt]);
                O1[dt] = mfma16(vfb, pf1b, O1[dt]);
                O2[dt] = mfma16(vfb, pf2b, O2[dt]);
            }
        }
    };

    auto finalize = [&]() {
        l1 += __shfl_xor(l1, 16); l1 += __shfl_xor(l1, 32);
        l2 += __shfl_xor(l2, 16); l2 += __shfl_xor(l2, 32);
        const float il1 = 1.0f / l1, il2 = lam / l2;
        unsigned short* op = attnb + (size_t)(b * S_LEN + qidx) * 1024 + h * 64;
#pragma unroll
        for (int dt = 0; dt < 4; dt++) {
            f32x4 o = O1[dt] * il1 - O2[dt] * il2;
            ushort4v t;
            t.x = f2bf(o[0]); t.y = f2bf(o[1]); t.z = f2bf(o[2]); t.w = f2bf(o[3]);
            *(ushort4v*)(op + dt * 16 + quad * 4) = t;
            s  += (o[0] + o[1]) + (o[2] + o[3]);
            ss += (o[0]*o[0] + o[1]*o[1]) + (o[2]*o[2] + o[3]*o[3]);
        }
    };

    // ---- shared phase: kt = 0 .. pair-1 (both sides, full tile, non-causal) ----
    for (int kt = 0; kt < pair; kt++) {
        __syncthreads();
        stage(kt + 1, (kt + 1) & 1);
        tile(kt, IntC<0>{}, IntC<4>{}, BoolC<false>{});
    }
    // ---- kt = pair: light diagonal (causal for side 0 only) ----
    {
        __syncthreads();
        stage(pair + 1, (pair + 1) & 1);       // pair+1 <= kmax always
        if (!side) tile(pair, IntC<0>{}, IntC<4>{}, BoolC<true>{});
        else       tile(pair, IntC<0>{}, IntC<4>{}, BoolC<false>{});
    }
    // ---- top-level phase switch: finalize light tile, swap to heavy rows ----
    if (!side) {
        finalize();
        f32x4 zero = {};
#pragma unroll
        for (int dt = 0; dt < 4; dt++) { O1[dt] = zero; O2[dt] = zero; }
        l1 = 0.f; l2 = 0.f;
        qidx = qtH * 64 + wq * 16 + col;
        const unsigned short* qh = QKV + (size_t)(b * S_LEN + qidx) * QKV_STRIDE + h * 128;
        q1f0 = *(const bf16x8*)(qh + quad * 8);
        q1f1 = *(const bf16x8*)(qh + 32 + quad * 8);
        q2f0 = *(const bf16x8*)(qh + 64 + quad * 8);
        q2f1 = *(const bf16x8*)(qh + 96 + quad * 8);
        rowt = -slope2 * (float)tok[b * S_LEN + qidx];
    }
    // ---- tail: kt = pair+1 .. kmax-1 (heavy only, key-split halves) ----
    for (int kt = pair + 1; kt < kmax; kt++) {
        __syncthreads();
        stage(kt + 1, (kt + 1) & 1);
        if (side) tile(kt, IntC<0>{}, IntC<2>{}, BoolC<false>{});
        else      tile(kt, IntC<2>{}, IntC<2>{}, BoolC<false>{});
    }
    // ---- kt = kmax: heavy diagonal (causal, key-split halves) ----
    {
        __syncthreads();
        if (side) tile(kmax, IntC<0>{}, IntC<2>{}, BoolC<true>{});
        else      tile(kmax, IntC<2>{}, IntC<2>{}, BoolC<true>{});
    }

    // combine tail partials: warps 0-3 -> warps 4-7 (same q-slice wq)
    __syncthreads();                           // last tile's LDS reads done
    float* comb = (float*)SMEM;
    if (!side) {
        float* p = comb + (size_t)(w * 64 + lane) * 36;
#pragma unroll
        for (int dt = 0; dt < 4; dt++) {
            *(f32x4*)(p + dt * 4)      = O1[dt];
            *(f32x4*)(p + 16 + dt * 4) = O2[dt];
        }
        p[32] = l1; p[33] = l2;
    }
    __syncthreads();
    if (side) {
        const float* p = comb + (size_t)((w - 4) * 64 + lane) * 36;
#pragma unroll
        for (int dt = 0; dt < 4; dt++) {
            O1[dt] += *(const f32x4*)(p + dt * 4);
            O2[dt] += *(const f32x4*)(p + 16 + dt * 4);
        }
        l1 += p[32]; l2 += p[33];
        finalize();                            // heavy tile -> store it
    }

    for (int off = 1; off < 64; off <<= 1) { s += __shfl_xor(s, off); ss += __shfl_xor(ss, off); }
    if (lane == 0) {
        atomicAdd(&sum_ws[bh], s);
        atomicAdd(&sumsq_ws[bh], ss);
    }
}

// -------------------- launch --------------------
extern "C" void kernel_launch(void* const* d_in, const int* in_sizes, int n_in,
                              void* d_out, int out_size, void* d_ws, size_t ws_size,
                              hipStream_t stream) {
    const float* inputs = (const float*)d_in[0];
    const float* amask  = (const float*)d_in[1];
    const int*   tok    = (const int*)d_in[2];
    const float* Wq     = (const float*)d_in[3];
    const float* Wk     = (const float*)d_in[4];
    const float* Wv     = (const float*)d_in[5];
    const float* Wo     = (const float*)d_in[6];
    const float* lq1    = (const float*)d_in[7];
    const float* lq2    = (const float*)d_in[8];
    const float* lk1    = (const float*)d_in[9];
    const float* lk2    = (const float*)d_in[10];
    const float* gamma  = (const float*)d_in[11];
    const float* beta   = (const float*)d_in[12];
    float* out = (float*)d_out;

    char* ws = (char*)d_ws;
    float* lam_ws   = (float*)ws;
    float* sum_ws   = (float*)(ws + 256);
    float* sumsq_ws = (float*)(ws + 512);
    float* colt_g   = (float*)(ws + 1024);          // 65536 floats = 256 KB
    unsigned short* Wob   = (unsigned short*)(ws + 1024 + 262144);
    unsigned short* QKVb  = Wob + 1048576;          // 4096 x 5120
    unsigned short* Xb    = QKVb + 20971520;        // 4096 x 1024
    unsigned short* Wqkvb = Xb + 4194304;           // 5120 x 1024
    unsigned short* VTb   = Wqkvb + 5242880;        // 32 x 64 x 2048
    unsigned short* attnb = Xb;                     // alias (X dead after QKV GEMM)

    cvt5lam_kernel<<<10304, 256, 0, stream>>>(inputs, Wq, Wk, Wv, Wo, Xb, Wqkvb, Wob,
                                              lq1, lk1, lq2, lk2, tok, amask,
                                              lam_ws, sum_ws, sumsq_ws, colt_g);
    gemm_bt<true, true, false, false, true><<<1280, 256, 0, stream>>>(
        Xb, Wqkvb, QKVb, VTb, nullptr, nullptr, nullptr, nullptr, 4096, 5120, 1024);
    attn_kernel<<<512, 512, 0, stream>>>(QKVb, VTb, tok, colt_g, lam_ws,
                                         attnb, sum_ws, sumsq_ws);
    gemm_bt<false, false, true, true, false><<<dim3(16, 32), 256, 0, stream>>>(
        attnb, Wob, out, nullptr, sum_ws, sumsq_ws, gamma, beta, 4096, 1024, 1024);
}